// Round 10
// baseline (137.374 us; speedup 1.0000x reference)
//
#include <hip/hip_runtime.h>

// SpatialTransformer: per-batch 3x3 homography warp + bilinear sample of
// image channel 0. image: (B,128,128,3) f32, H: (B,3,3) f32,
// out: (B,128,128,1) f32. B = 2048.
//
// R10: software-pipelined multi-image blocks. Each 1024-thread block owns
// 8 consecutive images and ping-pongs two 64KB LDS ch0-plane buffers
// (128KB total -> 1 block/CU). Per image k: issue image k+1's 12 dwordx4
// into registers FIRST, compute image k from LDS (the ~45us of VALU+store
// hides the fetch), then waitcnt+repack+ds_write_b128 into the other
// buffer, barrier. HBM fetch streams continuously instead of stalling at
// every stage/compute phase boundary (R7's limiter).
// Stage pattern = R7's proven strided-dwordx4 (beat R9's scatter variant).
// Coordinate math bit-identical to np reference (R3: output discontinuous
// at clamp boundaries; exact IEEE divide, same op order).

#define IMG_H 128
#define IMG_W 128
#define NPIX  (IMG_H * IMG_W)    // 16384
#define NFLT  (NPIX * 3)         // 49152
#define TPB   1024
#define KIMG  8                  // images per block

typedef float f32x4 __attribute__((ext_vector_type(4)));

__global__ __launch_bounds__(TPB, 4) void st_warp_kernel(
    const float* __restrict__ img,   // B*128*128*3
    const float* __restrict__ Hm,    // B*9
    float* __restrict__ out)         // B*128*128
{
    extern __shared__ float sh[];    // 2 * NPIX floats (128 KB)
    const int t  = threadIdx.x;
    const int b0 = blockIdx.x * KIMG;

    // ---- prologue: stage image b0 into buffer 0 (R7 pattern) ----
    {
        const float* imb = img + (size_t)b0 * NFLT;
        #pragma unroll
        for (int p = 0; p < 4; ++p) {
            const int c = t + p * TPB;               // chunk of 12 floats
            const float* src = imb + c * 12;
            const f32x4 v0 = *reinterpret_cast<const f32x4*>(src);
            const f32x4 v1 = *reinterpret_cast<const f32x4*>(src + 4);
            const f32x4 v2 = *reinterpret_cast<const f32x4*>(src + 8);
            f32x4 w;
            w.x = v0.x; w.y = v0.w; w.z = v1.z; w.w = v2.y;  // ch0 of 4 px
            *reinterpret_cast<f32x4*>(&sh[c * 4]) = w;
        }
    }
    __syncthreads();

    const float step = 2.0f / 127.0f;

    #pragma unroll 1
    for (int k = 0; k < KIMG; ++k) {
        const int b = b0 + k;

        // ---- issue next image's loads (held in regs across compute) ----
        f32x4 r[12];
        if (k + 1 < KIMG) {
            const float* imn = img + (size_t)(b + 1) * NFLT;
            #pragma unroll
            for (int p = 0; p < 4; ++p) {
                const int c = t + p * TPB;
                const float* src = imn + c * 12;
                r[p * 3 + 0] = *reinterpret_cast<const f32x4*>(src);
                r[p * 3 + 1] = *reinterpret_cast<const f32x4*>(src + 4);
                r[p * 3 + 2] = *reinterpret_cast<const f32x4*>(src + 8);
            }
        }

        // ---- compute image k from buf[k&1] ----
        const float* buf = sh + (k & 1) * NPIX;
        const float* Hb = Hm + b * 9;   // uniform -> scalar loads
        const float h00 = Hb[0], h01 = Hb[1], h02 = Hb[2];
        const float h10 = Hb[3], h11 = Hb[4], h12 = Hb[5];
        const float h20 = Hb[6], h21 = Hb[7], h22 = Hb[8];
        float* outb = out + (size_t)b * NPIX;

        #pragma unroll 1
        for (int q = 0; q < NPIX / TPB; ++q) {   // 16 pixels/thread
            const int n = t + q * TPB;
            const int i = n >> 7;     // row (wave-uniform-ish)
            const int j = n & 127;    // col (consecutive lanes)

            // coordinates: bit-identical to reference
            const float yt = -1.0f + step * (float)i;
            const float xt = -1.0f + step * (float)j;
            const float Tx = h00 * xt + h01 * yt + h02;
            const float Ty = h10 * xt + h11 * yt + h12;
            const float Tz = h20 * xt + h21 * yt + h22;
            const float x = (Tx / Tz + 1.0f) * 64.0f;   // exact IEEE divide
            const float y = (Ty / Tz + 1.0f) * 64.0f;

            int x0 = (int)fmaxf(fminf(floorf(x), 2.0e9f), -2.0e9f);
            int y0 = (int)fmaxf(fminf(floorf(y), 2.0e9f), -2.0e9f);
            int x1 = x0 + 1, y1 = y0 + 1;
            x0 = min(max(x0, 0), IMG_W - 1);
            x1 = min(max(x1, 0), IMG_W - 1);
            y0 = min(max(y0, 0), IMG_H - 1);
            y1 = min(max(y1, 0), IMG_H - 1);
            const int xl = min(x0, IMG_W - 2);

            const float lo0 = buf[(y0 << 7) + xl];
            const float hi0 = buf[(y0 << 7) + xl + 1];
            const float lo1 = buf[(y1 << 7) + xl];
            const float hi1 = buf[(y1 << 7) + xl + 1];
            const float Ia = (x0 > xl) ? hi0 : lo0;
            const float Ic = (x1 > xl) ? hi0 : lo0;
            const float Ib = (x0 > xl) ? hi1 : lo1;
            const float Id = (x1 > xl) ? hi1 : lo1;

            const float x0f = (float)x0, x1f = (float)x1;
            const float y0f = (float)y0, y1f = (float)y1;
            const float wa = (x1f - x) * (y1f - y);
            const float wb = (x1f - x) * (y - y0f);
            const float wc = (x - x0f) * (y1f - y);
            const float wd = (x - x0f) * (y - y0f);

            __builtin_nontemporal_store(wa * Ia + wb * Ib + wc * Ic + wd * Id,
                                        outb + n);
        }

        // ---- drain loads, repack, write next buffer ----
        if (k + 1 < KIMG) {
            float* nbuf = sh + ((k + 1) & 1) * NPIX;
            #pragma unroll
            for (int p = 0; p < 4; ++p) {
                const int c = t + p * TPB;
                f32x4 w;
                w.x = r[p * 3 + 0].x;
                w.y = r[p * 3 + 0].w;
                w.z = r[p * 3 + 1].z;
                w.w = r[p * 3 + 2].y;
                *reinterpret_cast<f32x4*>(&nbuf[c * 4]) = w;
            }
        }
        __syncthreads();
    }
}

extern "C" void kernel_launch(void* const* d_in, const int* in_sizes, int n_in,
                              void* d_out, int out_size, void* d_ws, size_t ws_size,
                              hipStream_t stream) {
    const float* img = (const float*)d_in[0];   // (2048,128,128,3) f32
    const float* Hm  = (const float*)d_in[1];   // (2048,3,3) f32
    float* out = (float*)d_out;                 // (2048,128,128,1) f32

    const int B = in_sizes[1] / 9;              // 2048
    const size_t lds_bytes = 2 * NPIX * sizeof(float);   // 128 KB

    static bool attr_set = false;               // host-side only; idempotent
    if (!attr_set) {
        hipFuncSetAttribute((const void*)st_warp_kernel,
                            hipFuncAttributeMaxDynamicSharedMemorySize,
                            (int)lds_bytes);
        attr_set = true;
    }

    st_warp_kernel<<<B / KIMG, TPB, lds_bytes, stream>>>(img, Hm, out);
}

// Round 11
// 105.586 us; speedup vs baseline: 1.3011x; 1.3011x over previous
//
#include <hip/hip_runtime.h>

// SpatialTransformer: per-batch 3x3 homography warp + bilinear sample of
// image channel 0. image: (B,128,128,3) f32, H: (B,3,3) f32,
// out: (B,128,128,1) f32. B = 2048.
//
// R11 = R7 (one block/image, 64KB f32 ch0 plane in LDS, R7's proven
// strided-dwordx4 staging, NT store) with the exact IEEE divides replaced
// by a shared Newton-refined rcp (error ~2ulp). The reference output is
// discontinuous ONLY at the clamp lines x,y in {0,127} (outside: weights
// cancel to 0; inside: edge value) -- everywhere else it is continuous and
// the harness compares after bf16 rounding, so ~1e-5 coordinate error is
// invisible. Pixels within 2e-3 of a clamp line (or |Tz| ~ 0) recompute
// x,y BIT-EXACTLY with IEEE divides under an execz-skipped branch
// (~100 of 33.5M pixels -> no divergence cost). Margin 2e-3 >> fast error
// 3e-5, so every ambiguous pixel takes the exact path and floors match np.

#define IMG_H 128
#define IMG_W 128
#define NPIX  (IMG_H * IMG_W)    // 16384
#define NFLT  (NPIX * 3)         // 49152
#define TPB   1024

typedef float f32x4 __attribute__((ext_vector_type(4)));

__global__ __launch_bounds__(TPB, 8) void st_warp_kernel(
    const float* __restrict__ img,   // B*128*128*3
    const float* __restrict__ Hm,    // B*9
    float* __restrict__ out)         // B*128*128
{
    __shared__ float sh[NPIX];       // ch0 plane, 65536 B

    const int b = blockIdx.x;
    const int t = threadIdx.x;
    const float* imb = img + (size_t)b * NFLT;

    const float* Hb = Hm + b * 9;    // uniform across block -> scalar loads
    const float h00 = Hb[0], h01 = Hb[1], h02 = Hb[2];
    const float h10 = Hb[3], h11 = Hb[4], h12 = Hb[5];
    const float h20 = Hb[6], h21 = Hb[7], h22 = Hb[8];

    // ---- stage: 4096 chunks of 12 floats -> 4 contiguous LDS floats ----
    #pragma unroll
    for (int p = 0; p < 4; ++p) {
        const int c = t + p * TPB;               // chunk id, < 4096
        const float* src = imb + c * 12;         // 48B-aligned
        const f32x4 v0 = *reinterpret_cast<const f32x4*>(src);
        const f32x4 v1 = *reinterpret_cast<const f32x4*>(src + 4);
        const f32x4 v2 = *reinterpret_cast<const f32x4*>(src + 8);
        f32x4 w;
        w.x = v0.x;   // ch0 of px 4c+0
        w.y = v0.w;   // ch0 of px 4c+1
        w.z = v1.z;   // ch0 of px 4c+2
        w.w = v2.y;   // ch0 of px 4c+3
        *reinterpret_cast<f32x4*>(&sh[c * 4]) = w;   // ds_write_b128
    }
    __syncthreads();

    const float step = 2.0f / 127.0f;
    float* outb = out + (size_t)b * NPIX;

    #pragma unroll 1
    for (int k = 0; k < NPIX / TPB; ++k) {   // 16 pixels/thread
        const int n = t + k * TPB;
        const int i = n >> 7;     // row: wave's 64 lanes share one row
        const int j = n & 127;    // col: consecutive lanes -> consecutive cols

        const float yt = -1.0f + step * (float)i;
        const float xt = -1.0f + step * (float)j;
        const float Tx = h00 * xt + h01 * yt + h02;
        const float Ty = h10 * xt + h11 * yt + h12;
        const float Tz = h20 * xt + h21 * yt + h22;

        // ---- fast shared-reciprocal coordinates (err ~2ulp) ----
        const float r0 = __builtin_amdgcn_rcpf(Tz);
        const float rz = fmaf(fmaf(-Tz, r0, 1.0f), r0, r0);   // Newton
        float x = (Tx * rz + 1.0f) * 64.0f;
        float y = (Ty * rz + 1.0f) * 64.0f;

        // ---- exact fallback near the discontinuous clamp lines ----
        const float m = 2.0e-3f;
        const bool danger =
            (fabsf(x) < m) | (fabsf(x - 127.0f) < m) |
            (fabsf(y) < m) | (fabsf(y - 127.0f) < m) |
            !(fabsf(Tz) > 1.0e-20f);
        if (danger) {   // execz-skipped when no lane flagged (~always)
            x = (Tx / Tz + 1.0f) * 64.0f;   // exact IEEE divide = np bits
            y = (Ty / Tz + 1.0f) * 64.0f;
        }

        int x0 = (int)fmaxf(fminf(floorf(x), 2.0e9f), -2.0e9f);
        int y0 = (int)fmaxf(fminf(floorf(y), 2.0e9f), -2.0e9f);
        int x1 = x0 + 1, y1 = y0 + 1;
        x0 = min(max(x0, 0), IMG_W - 1);
        x1 = min(max(x1, 0), IMG_W - 1);
        y0 = min(max(y0, 0), IMG_H - 1);
        y1 = min(max(y1, 0), IMG_H - 1);
        const int xl = min(x0, IMG_W - 2);   // [xl, xl+1] covers x0 and x1

        // ---- LDS gather (pairs -> ds_read2_b32) ----
        const float lo0 = sh[(y0 << 7) + xl];
        const float hi0 = sh[(y0 << 7) + xl + 1];
        const float lo1 = sh[(y1 << 7) + xl];
        const float hi1 = sh[(y1 << 7) + xl + 1];
        const float Ia = (x0 > xl) ? hi0 : lo0;
        const float Ic = (x1 > xl) ? hi0 : lo0;
        const float Ib = (x0 > xl) ? hi1 : lo1;
        const float Id = (x1 > xl) ? hi1 : lo1;

        // ---- blend (weights from CLIPPED indices = ref semantics) ----
        const float x0f = (float)x0, x1f = (float)x1;
        const float y0f = (float)y0, y1f = (float)y1;
        const float wa = (x1f - x) * (y1f - y);
        const float wb = (x1f - x) * (y - y0f);
        const float wc = (x - x0f) * (y1f - y);
        const float wd = (x - x0f) * (y - y0f);

        __builtin_nontemporal_store(wa * Ia + wb * Ib + wc * Ic + wd * Id,
                                    outb + n);
    }
}

extern "C" void kernel_launch(void* const* d_in, const int* in_sizes, int n_in,
                              void* d_out, int out_size, void* d_ws, size_t ws_size,
                              hipStream_t stream) {
    const float* img = (const float*)d_in[0];   // (2048,128,128,3) f32
    const float* Hm  = (const float*)d_in[1];   // (2048,3,3) f32
    float* out = (float*)d_out;                 // (2048,128,128,1) f32

    const int B = in_sizes[1] / 9;              // 2048 blocks, 1 image each
    st_warp_kernel<<<B, TPB, 0, stream>>>(img, Hm, out);
}

// Round 12
// 105.339 us; speedup vs baseline: 1.3041x; 1.0023x over previous
//
#include <hip/hip_runtime.h>

// SpatialTransformer: per-batch 3x3 homography warp + bilinear sample of
// image channel 0. image: (B,128,128,3) f32, H: (B,3,3) f32,
// out: (B,128,128,1) f32. B = 2048.
//
// R12 = R11 (LDS ch0 plane, Newton-rcp fast path + bit-exact IEEE-divide
// fallback within 2e-3 of the discontinuous clamp lines) with the fast
// path's VALU minimized:
//  - pre-scaled block-uniform coefficients: x = Tx2*rz where
//    Tx2 = 64*(Tx+Tz) (fold the +1 and *64 into H once per block, SALU)
//  - xt-terms hoisted out of the k-loop (j = t&127 is loop-invariant)
//  - incremental yt (+8*step per iteration)
// Fast-path coords: 3 FMA + rcp + 2 FMA + 2 MUL = 8 VALU ops. Fallback
// branch recomputes from the ORIGINAL h coefficients with exact divides
// (np-bit-identical), so clamp-line pixels stay exact.

#define IMG_H 128
#define IMG_W 128
#define NPIX  (IMG_H * IMG_W)    // 16384
#define NFLT  (NPIX * 3)         // 49152
#define TPB   1024

typedef float f32x4 __attribute__((ext_vector_type(4)));

__global__ __launch_bounds__(TPB, 8) void st_warp_kernel(
    const float* __restrict__ img,   // B*128*128*3
    const float* __restrict__ Hm,    // B*9
    float* __restrict__ out)         // B*128*128
{
    __shared__ float sh[NPIX];       // ch0 plane, 65536 B

    const int b = blockIdx.x;
    const int t = threadIdx.x;
    const float* imb = img + (size_t)b * NFLT;

    const float* Hb = Hm + b * 9;    // uniform across block -> scalar loads
    const float h00 = Hb[0], h01 = Hb[1], h02 = Hb[2];
    const float h10 = Hb[3], h11 = Hb[4], h12 = Hb[5];
    const float h20 = Hb[6], h21 = Hb[7], h22 = Hb[8];

    // ---- stage: 4096 chunks of 12 floats -> 4 contiguous LDS floats ----
    #pragma unroll
    for (int p = 0; p < 4; ++p) {
        const int c = t + p * TPB;               // chunk id, < 4096
        const float* src = imb + c * 12;         // 48B-aligned
        const f32x4 v0 = *reinterpret_cast<const f32x4*>(src);
        const f32x4 v1 = *reinterpret_cast<const f32x4*>(src + 4);
        const f32x4 v2 = *reinterpret_cast<const f32x4*>(src + 8);
        f32x4 w;
        w.x = v0.x; w.y = v0.w; w.z = v1.z; w.w = v2.y;  // ch0 of 4 px
        *reinterpret_cast<f32x4*>(&sh[c * 4]) = w;       // ds_write_b128
    }
    __syncthreads();

    const float step = 2.0f / 127.0f;
    float* outb = out + (size_t)b * NPIX;

    // Block-uniform pre-scaled coefficients (SALU, once):
    // x = ((Tx/Tz)+1)*64 = (64*(Tx+Tz))/Tz  ->  Tx2 coeffs = 64*(h0k+h2k)
    const float Ax = 64.0f * (h00 + h20), Bx = 64.0f * (h01 + h21),
                Cx = 64.0f * (h02 + h22);
    const float Ay = 64.0f * (h10 + h20), By = 64.0f * (h11 + h21),
                Cy = 64.0f * (h12 + h22);

    // Per-thread hoisted xt-terms (j = t & 127 is k-invariant):
    const int j = t & 127;
    const float xt  = -1.0f + step * (float)j;   // exact ref expression
    const float xcx = fmaf(Ax, xt, Cx);
    const float xcy = fmaf(Ay, xt, Cy);
    const float xcz = fmaf(h20, xt, h22);

    const int   i0   = t >> 7;                   // starting row
    float       ytf  = -1.0f + step * (float)i0; // fast-path yt (incremental)
    const float dyt  = 8.0f * step;              // rows advance by 8 per k

    #pragma unroll 1
    for (int k = 0; k < NPIX / TPB; ++k) {   // 16 pixels/thread
        const int n = t + k * TPB;
        const int i = i0 + k * 8;

        // ---- fast coords: 3 FMA + rcp + 2 FMA + 2 MUL ----
        const float Tz  = fmaf(h21, ytf, xcz);
        const float Tx2 = fmaf(Bx,  ytf, xcx);
        const float Ty2 = fmaf(By,  ytf, xcy);
        const float r0  = __builtin_amdgcn_rcpf(Tz);
        const float rz  = fmaf(fmaf(-Tz, r0, 1.0f), r0, r0);   // Newton
        float x = Tx2 * rz;
        float y = Ty2 * rz;

        // ---- exact fallback near the discontinuous clamp lines ----
        const float m = 2.0e-3f;
        const bool danger =
            (fabsf(x) < m) | (fabsf(x - 127.0f) < m) |
            (fabsf(y) < m) | (fabsf(y - 127.0f) < m) |
            !(fabsf(Tz) > 1.0e-20f);
        if (danger) {   // execz-skipped when no lane flagged (~always)
            const float yte = -1.0f + step * (float)i;   // exact ref bits
            const float Txe = h00 * xt + h01 * yte + h02;
            const float Tye = h10 * xt + h11 * yte + h12;
            const float Tze = h20 * xt + h21 * yte + h22;
            x = (Txe / Tze + 1.0f) * 64.0f;   // exact IEEE divide = np bits
            y = (Tye / Tze + 1.0f) * 64.0f;
        }

        int x0 = (int)fmaxf(fminf(floorf(x), 2.0e9f), -2.0e9f);
        int y0 = (int)fmaxf(fminf(floorf(y), 2.0e9f), -2.0e9f);
        int x1 = x0 + 1, y1 = y0 + 1;
        x0 = min(max(x0, 0), IMG_W - 1);
        x1 = min(max(x1, 0), IMG_W - 1);
        y0 = min(max(y0, 0), IMG_H - 1);
        y1 = min(max(y1, 0), IMG_H - 1);
        const int xl = min(x0, IMG_W - 2);   // [xl, xl+1] covers x0 and x1

        // ---- LDS gather (pairs -> ds_read2_b32) ----
        const float lo0 = sh[(y0 << 7) + xl];
        const float hi0 = sh[(y0 << 7) + xl + 1];
        const float lo1 = sh[(y1 << 7) + xl];
        const float hi1 = sh[(y1 << 7) + xl + 1];
        const float Ia = (x0 > xl) ? hi0 : lo0;
        const float Ic = (x1 > xl) ? hi0 : lo0;
        const float Ib = (x0 > xl) ? hi1 : lo1;
        const float Id = (x1 > xl) ? hi1 : lo1;

        // ---- blend (weights from CLIPPED indices = ref semantics) ----
        const float x0f = (float)x0, x1f = (float)x1;
        const float y0f = (float)y0, y1f = (float)y1;
        const float wa = (x1f - x) * (y1f - y);
        const float wb = (x1f - x) * (y - y0f);
        const float wc = (x - x0f) * (y1f - y);
        const float wd = (x - x0f) * (y - y0f);

        __builtin_nontemporal_store(wa * Ia + wb * Ib + wc * Ic + wd * Id,
                                    outb + n);

        ytf += dyt;   // incremental fast-path row coordinate
    }
}

extern "C" void kernel_launch(void* const* d_in, const int* in_sizes, int n_in,
                              void* d_out, int out_size, void* d_ws, size_t ws_size,
                              hipStream_t stream) {
    const float* img = (const float*)d_in[0];   // (2048,128,128,3) f32
    const float* Hm  = (const float*)d_in[1];   // (2048,3,3) f32
    float* out = (float*)d_out;                 // (2048,128,128,1) f32

    const int B = in_sizes[1] / 9;              // 2048 blocks, 1 image each
    st_warp_kernel<<<B, TPB, 0, stream>>>(img, Hm, out);
}